// Round 1
// baseline (445.456 us; speedup 1.0000x reference)
//
#include <hip/hip_runtime.h>

typedef _Float16 f16;
typedef _Float16 f16x8 __attribute__((ext_vector_type(8)));
typedef _Float16 f16x4 __attribute__((ext_vector_type(4)));
typedef float    f32x4 __attribute__((ext_vector_type(4)));

static constexpr int BATCH = 2, SEQ = 2048, DMODEL = 1024, HEADS = 16, DHEAD = 64;
static constexpr int MTOK = BATCH * SEQ;  // 4096 tokens

// async global->LDS, 16B per lane, LDS dest = wave-uniform base + lane*16
#define GLOBAL_LOAD_LDS16(gptr, lptr)                                              \
  __builtin_amdgcn_global_load_lds(                                                \
      (const __attribute__((address_space(1))) void*)(gptr),                       \
      (__attribute__((address_space(3))) void*)(lptr), 16, 0, 0)

// ---------------- cast fp32 -> fp16, 4 elems/thread ----------------
__global__ __launch_bounds__(256) void cast_kernel(const float* __restrict__ src,
                                                   f16* __restrict__ dst) {
  int i = blockIdx.x * 256 + threadIdx.x;
  f32x4 x = ((const f32x4*)src)[i];
  f16x4 y;
  y[0] = (f16)x[0]; y[1] = (f16)x[1]; y[2] = (f16)x[2]; y[3] = (f16)x[3];
  ((f16x4*)dst)[i] = y;
}

// ------------- weight transpose+cast: t[n][k] = (f16) w[k][n] -------------
__global__ __launch_bounds__(256) void transw_kernel(
    const float* __restrict__ w0, const float* __restrict__ w1,
    const float* __restrict__ w2, const float* __restrict__ w3,
    f16* __restrict__ t0, f16* __restrict__ t1,
    f16* __restrict__ t2, f16* __restrict__ t3) {
  const int z = blockIdx.z;
  const float* w = z == 0 ? w0 : z == 1 ? w1 : z == 2 ? w2 : w3;
  f16* t        = z == 0 ? t0 : z == 1 ? t1 : z == 2 ? t2 : t3;
  __shared__ f16 lt[64][72];  // 72*2B = 144B row stride, keeps 16B reads aligned
  const int k0 = blockIdx.x * 64, n0 = blockIdx.y * 64;
  const int r = threadIdx.x >> 2, c0 = (threadIdx.x & 3) * 16;
  const float* src = w + (size_t)(k0 + r) * DMODEL + n0 + c0;
#pragma unroll
  for (int j = 0; j < 16; j += 4) {
    f32x4 x = *(const f32x4*)(src + j);
    lt[c0 + j + 0][r] = (f16)x[0];
    lt[c0 + j + 1][r] = (f16)x[1];
    lt[c0 + j + 2][r] = (f16)x[2];
    lt[c0 + j + 3][r] = (f16)x[3];
  }
  __syncthreads();
  f16* dst = t + (size_t)(n0 + r) * DMODEL + k0 + c0;
  *(f16x8*)(dst)     = *(const f16x8*)&lt[r][c0];
  *(f16x8*)(dst + 8) = *(const f16x8*)&lt[r][c0 + 8];
}

// ---------------- GEMM: C[M,N=1024] = A[M,K] @ Bt[N,K]^T + bias ----------------
// 128x128 tile, BK=32, 512 threads (8 waves, 2x4 wave grid, 64x32 per wave).
// EPI 0: f16 linear out; EPI 1: f16 scatter to Vt[b,h,dh,s]; EPI 2: f32 linear out.
template <int EPI>
__global__ __launch_bounds__(512) void gemm_kernel(
    const f16* __restrict__ A, const f16* __restrict__ Bt,
    const float* __restrict__ bias, void* __restrict__ Cout, int K) {
  __shared__ f16 As[128 * 32];
  __shared__ f16 Bs[128 * 32];
  const int tid = threadIdx.x;
  const int w = tid >> 6, l = tid & 63, q = l & 15, g = l >> 4;
  const int m0 = blockIdx.y * 128, n0 = blockIdx.x * 128;
  const int wr = w >> 2, wc = w & 3;
  // staging map: wave w covers rows [w*16, w*16+16), lane lays 16B at base+l*16
  const int srow = w * 16 + (l >> 2), scol = (l & 3) * 8;
  f32x4 acc[4][2] = {};
  const f16* ga = A + (size_t)(m0 + srow) * K + scol;
  const f16* gb = Bt + (size_t)(n0 + srow) * K + scol;
  f16* lA = &As[w * 512];
  f16* lB = &Bs[w * 512];
  for (int kt = 0; kt < K; kt += 32) {
    GLOBAL_LOAD_LDS16(ga + kt, lA);
    GLOBAL_LOAD_LDS16(gb + kt, lB);
    __syncthreads();
    f16x8 af[4], bf[2];
#pragma unroll
    for (int mi = 0; mi < 4; mi++)
      af[mi] = *(const f16x8*)&As[(wr * 64 + mi * 16 + q) * 32 + g * 8];
#pragma unroll
    for (int ni = 0; ni < 2; ni++)
      bf[ni] = *(const f16x8*)&Bs[(wc * 32 + ni * 16 + q) * 32 + g * 8];
#pragma unroll
    for (int mi = 0; mi < 4; mi++)
#pragma unroll
      for (int ni = 0; ni < 2; ni++)
        acc[mi][ni] = __builtin_amdgcn_mfma_f32_16x16x32_f16(af[mi], bf[ni], acc[mi][ni], 0, 0, 0);
    __syncthreads();
  }
#pragma unroll
  for (int mi = 0; mi < 4; mi++)
#pragma unroll
    for (int ni = 0; ni < 2; ni++) {
      const int col = n0 + wc * 32 + ni * 16 + q;
      const float bv = bias[col];
#pragma unroll
      for (int r = 0; r < 4; r++) {
        const int row = m0 + wr * 64 + mi * 16 + g * 4 + r;
        const float val = acc[mi][ni][r] + bv;
        if (EPI == 0) {
          ((f16*)Cout)[(size_t)row * DMODEL + col] = (f16)val;
        } else if (EPI == 1) {
          const int bb = row >> 11, s = row & (SEQ - 1);
          const int hh = col >> 6, dh = col & 63;
          ((f16*)Cout)[((size_t)((bb * HEADS + hh) * DHEAD + dh) << 11) + s] = (f16)val;
        } else {
          ((float*)Cout)[(size_t)row * DMODEL + col] = val;
        }
      }
    }
}

// ---------------- flash-style attention, NO 1/sqrt(dk) scaling ----------------
// grid (S/64, B*H); 4 waves; wave owns 16 q-rows; K-tile = 64.
// Writes attention output directly in the reference's "transpose-bug" scramble.
__global__ __launch_bounds__(256) void attn_kernel(
    const f16* __restrict__ Qp, const f16* __restrict__ Kp,
    const f16* __restrict__ Vt, f16* __restrict__ data_s) {
  __shared__ f16 Plds[4][16][72];  // per-wave P tile, 144B row stride
  const int tid = threadIdx.x;
  const int w = tid >> 6, l = tid & 63, q = l & 15, g = l >> 4;
  const int bh = blockIdx.y, b = bh >> 4, h = bh & 15;
  const int q0 = blockIdx.x * 64 + w * 16;
  const f16* qrow = Qp + (size_t)(b * SEQ + q0 + q) * DMODEL + h * DHEAD;
  f16x8 qf0 = *(const f16x8*)(qrow + g * 8);
  f16x8 qf1 = *(const f16x8*)(qrow + 32 + g * 8);
  const f16* kbase = Kp + (size_t)b * SEQ * DMODEL + h * DHEAD;
  const f16* vbase = Vt + (size_t)bh * DHEAD * SEQ;
  float m_st[4], l_st[4];
  f32x4 o_acc[4] = {};
#pragma unroll
  for (int r = 0; r < 4; r++) { m_st[r] = -__builtin_inff(); l_st[r] = 0.f; }

  for (int kt = 0; kt < SEQ; kt += 64) {
    // S = Q @ K^T : acc layout col=s_k(l&15), row=q(4g+r)
    f32x4 sacc[4];
#pragma unroll
    for (int fn = 0; fn < 4; fn++) {
      const f16* kr = kbase + (size_t)(kt + fn * 16 + q) * DMODEL;
      f16x8 k0 = *(const f16x8*)(kr + g * 8);
      f16x8 k1 = *(const f16x8*)(kr + 32 + g * 8);
      f32x4 z = {};
      z = __builtin_amdgcn_mfma_f32_16x16x32_f16(qf0, k0, z, 0, 0, 0);
      z = __builtin_amdgcn_mfma_f32_16x16x32_f16(qf1, k1, z, 0, 0, 0);
      sacc[fn] = z;
    }
    // online softmax: row reduce across the 16 lanes sharing g
    float sc[4];
#pragma unroll
    for (int r = 0; r < 4; r++) {
      float mx = fmaxf(fmaxf(sacc[0][r], sacc[1][r]), fmaxf(sacc[2][r], sacc[3][r]));
#pragma unroll
      for (int d = 1; d < 16; d <<= 1) mx = fmaxf(mx, __shfl_xor(mx, d, 64));
      const float mnew = fmaxf(m_st[r], mx);
      sc[r] = __expf(m_st[r] - mnew);  // 0 on first tile (m=-inf)
      m_st[r] = mnew;
    }
    float tsum[4] = {0.f, 0.f, 0.f, 0.f};
#pragma unroll
    for (int fn = 0; fn < 4; fn++) {
#pragma unroll
      for (int r = 0; r < 4; r++) {
        const float p = __expf(sacc[fn][r] - m_st[r]);
        tsum[r] += p;
        Plds[w][g * 4 + r][fn * 16 + q] = (f16)p;  // store P in [q][s_k] layout
      }
    }
#pragma unroll
    for (int r = 0; r < 4; r++) {
      float sm = tsum[r];
#pragma unroll
      for (int d = 1; d < 16; d <<= 1) sm += __shfl_xor(sm, d, 64);
      l_st[r] = l_st[r] * sc[r] + sm;
#pragma unroll
      for (int fo = 0; fo < 4; fo++) o_acc[fo][r] *= sc[r];
    }
    // PV: A = P (from LDS, A-layout), B = V^T rows (contiguous s)
    f16x8 pa0 = *(const f16x8*)&Plds[w][q][g * 8];
    f16x8 pa1 = *(const f16x8*)&Plds[w][q][32 + g * 8];
#pragma unroll
    for (int fo = 0; fo < 4; fo++) {
      const f16* vr = vbase + (size_t)(fo * 16 + q) * SEQ + kt;
      f16x8 v0 = *(const f16x8*)(vr + g * 8);
      f16x8 v1 = *(const f16x8*)(vr + 32 + g * 8);
      o_acc[fo] = __builtin_amdgcn_mfma_f32_16x16x32_f16(pa0, v0, o_acc[fo], 0, 0, 0);
      o_acc[fo] = __builtin_amdgcn_mfma_f32_16x16x32_f16(pa1, v1, o_acc[fo], 0, 0, 0);
    }
  }
  // finalize + scrambled store:
  // b'=h>>3, s'=((2h+b)&15)*128 + s/16, d'=(s%16)*64 + dh
  const int m16 = (2 * h + b) & 15, bp = h >> 3;
#pragma unroll
  for (int r = 0; r < 4; r++) {
    const int s = q0 + g * 4 + r;
    const int sp = m16 * 128 + (s >> 4);
    const float inv = 1.f / l_st[r];
#pragma unroll
    for (int fo = 0; fo < 4; fo++) {
      const int dp = (s & 15) * 64 + fo * 16 + q;
      data_s[(size_t)(bp * SEQ + sp) * DMODEL + dp] = (f16)(o_acc[fo][r] * inv);
    }
  }
}

extern "C" void kernel_launch(void* const* d_in, const int* in_sizes, int n_in,
                              void* d_out, int out_size, void* d_ws, size_t ws_size,
                              hipStream_t stream) {
  const float* q  = (const float*)d_in[0];
  const float* k  = (const float*)d_in[1];
  const float* v  = (const float*)d_in[2];
  const float* wq = (const float*)d_in[3];
  const float* bq = (const float*)d_in[4];
  const float* wk = (const float*)d_in[5];
  const float* bk = (const float*)d_in[6];
  const float* wv = (const float*)d_in[7];
  const float* bv = (const float*)d_in[8];
  const float* wo = (const float*)d_in[9];
  const float* bo = (const float*)d_in[10];

  // workspace layout (40 MB total):
  // [0,8M)   xb   : f16 cast of q/k/v in turn, later the scrambled attn output
  // [8,16M)  Qp   [16,24M) Kp   [24,32M) Vt[b,h,dh,s]
  // [32,40M) wqt/wkt/wvt/wot (f16, transposed [N][K], 2MB each)
  uint8_t* ws = (uint8_t*)d_ws;
  f16* xb  = (f16*)(ws);
  f16* Qp  = (f16*)(ws + (8u << 20));
  f16* Kp  = (f16*)(ws + (16u << 20));
  f16* Vt  = (f16*)(ws + (24u << 20));
  f16* wqt = (f16*)(ws + (32u << 20));
  f16* wkt = (f16*)(ws + (34u << 20));
  f16* wvt = (f16*)(ws + (36u << 20));
  f16* wot = (f16*)(ws + (38u << 20));

  dim3 blk256(256), blk512(512);
  dim3 gT(16, 16, 4);
  dim3 gC(MTOK * DMODEL / 4 / 256);       // 4096 blocks
  dim3 gG(DMODEL / 128, MTOK / 128);      // (8, 32)
  dim3 gA(SEQ / 64, BATCH * HEADS);       // (32, 32)

  transw_kernel<<<gT, blk256, 0, stream>>>(wq, wk, wv, wo, wqt, wkt, wvt, wot);

  cast_kernel<<<gC, blk256, 0, stream>>>(q, xb);
  gemm_kernel<0><<<gG, blk512, 0, stream>>>(xb, wqt, bq, Qp, DMODEL);

  cast_kernel<<<gC, blk256, 0, stream>>>(k, xb);
  gemm_kernel<0><<<gG, blk512, 0, stream>>>(xb, wkt, bk, Kp, DMODEL);

  cast_kernel<<<gC, blk256, 0, stream>>>(v, xb);
  gemm_kernel<1><<<gG, blk512, 0, stream>>>(xb, wvt, bv, Vt, DMODEL);

  attn_kernel<<<gA, blk256, 0, stream>>>(Qp, Kp, Vt, xb);
  gemm_kernel<2><<<gG, blk512, 0, stream>>>(xb, wot, bo, (float*)d_out, DMODEL);
}

// Round 2
// 267.498 us; speedup vs baseline: 1.6653x; 1.6653x over previous
//
#include <hip/hip_runtime.h>

typedef _Float16 f16;
typedef _Float16 f16x8 __attribute__((ext_vector_type(8)));
typedef _Float16 f16x4 __attribute__((ext_vector_type(4)));
typedef float    f32x4 __attribute__((ext_vector_type(4)));

static constexpr int BATCH = 2, SEQ = 2048, DMODEL = 1024, HEADS = 16, DHEAD = 64;
static constexpr int MTOK = BATCH * SEQ;  // 4096 tokens

// async global->LDS, 16B per lane, LDS dest = wave-uniform base + lane*16
#define GLOBAL_LOAD_LDS16(gptr, lptr)                                              \
  __builtin_amdgcn_global_load_lds(                                                \
      (const __attribute__((address_space(1))) void*)(gptr),                       \
      (__attribute__((address_space(3))) void*)(lptr), 16, 0, 0)

#define MFMA16(a, b, c) __builtin_amdgcn_mfma_f32_16x16x32_f16((a), (b), (c), 0, 0, 0)

// ---------------- cast fp32 -> fp16, 4 elems/thread ----------------
__global__ __launch_bounds__(256) void cast_kernel(const float* __restrict__ src,
                                                   f16* __restrict__ dst) {
  int i = blockIdx.x * 256 + threadIdx.x;
  f32x4 x = ((const f32x4*)src)[i];
  f16x4 y;
  y[0] = (f16)x[0]; y[1] = (f16)x[1]; y[2] = (f16)x[2]; y[3] = (f16)x[3];
  ((f16x4*)dst)[i] = y;
}

// ------------- weight transpose+cast: t[n][k] = (f16) w[k][n] -------------
__global__ __launch_bounds__(256) void transw_kernel(
    const float* __restrict__ w0, const float* __restrict__ w1,
    const float* __restrict__ w2, const float* __restrict__ w3,
    f16* __restrict__ t0, f16* __restrict__ t1,
    f16* __restrict__ t2, f16* __restrict__ t3) {
  const int z = blockIdx.z;
  const float* w = z == 0 ? w0 : z == 1 ? w1 : z == 2 ? w2 : w3;
  f16* t        = z == 0 ? t0 : z == 1 ? t1 : z == 2 ? t2 : t3;
  __shared__ f16 lt[64][72];
  const int k0 = blockIdx.x * 64, n0 = blockIdx.y * 64;
  const int r = threadIdx.x >> 2, c0 = (threadIdx.x & 3) * 16;
  const float* src = w + (size_t)(k0 + r) * DMODEL + n0 + c0;
#pragma unroll
  for (int j = 0; j < 16; j += 4) {
    f32x4 x = *(const f32x4*)(src + j);
    lt[c0 + j + 0][r] = (f16)x[0];
    lt[c0 + j + 1][r] = (f16)x[1];
    lt[c0 + j + 2][r] = (f16)x[2];
    lt[c0 + j + 3][r] = (f16)x[3];
  }
  __syncthreads();
  f16* dst = t + (size_t)(n0 + r) * DMODEL + k0 + c0;
  *(f16x8*)(dst)     = *(const f16x8*)&lt[r][c0];
  *(f16x8*)(dst + 8) = *(const f16x8*)&lt[r][c0 + 8];
}

// ---------------- GEMM: C[M,N=1024] = A[M,K] @ Bt[N,K]^T + bias ----------------
// 128x64 tile, BK=64, 256 threads (4 waves, 2x2 wave grid, 64x32 per wave).
// Double-buffered LDS, XOR-swizzled rows, global_load_lds staging, 2-phase.
// EPI 0: f16 linear out; EPI 1: f16 scatter to Vt[b,h,dh,s]; EPI 2: f32 linear out.
template <int EPI>
__global__ __launch_bounds__(256) void gemm_kernel(
    const f16* __restrict__ A, const f16* __restrict__ Bt,
    const float* __restrict__ bias, void* __restrict__ Cout, int K) {
  __shared__ f16 As[2][128][64];
  __shared__ f16 Bs[2][64][64];
  const int tid = threadIdx.x;
  const int w = tid >> 6, l = tid & 63, q = l & 15, g = l >> 4;
  const int wr = w >> 1, wc = w & 1;
  const int m0 = blockIdx.y * 128, n0 = blockIdx.x * 64;
  const int sr = l >> 3, sc8 = l & 7;
  const int swz = q & 7;
  f32x4 acc[4][2] = {};
  const int NT = K / 64;

#define GEMM_STAGE(bb, kt)                                                         \
  {                                                                                \
    _Pragma("unroll")                                                              \
    for (int j = 0; j < 4; j++) {                                                  \
      const int rr_ = w * 32 + j * 8 + sr;                                         \
      const int cs_ = sc8 ^ (rr_ & 7);                                             \
      GLOBAL_LOAD_LDS16(A + (size_t)(m0 + rr_) * K + (kt) + cs_ * 8,               \
                        (char*)&As[bb][w * 32 + j * 8][0]);                        \
    }                                                                              \
    _Pragma("unroll")                                                              \
    for (int j = 0; j < 2; j++) {                                                  \
      const int rr_ = w * 16 + j * 8 + sr;                                         \
      const int cs_ = sc8 ^ (rr_ & 7);                                             \
      GLOBAL_LOAD_LDS16(Bt + (size_t)(n0 + rr_) * K + (kt) + cs_ * 8,              \
                        (char*)&Bs[bb][w * 16 + j * 8][0]);                        \
    }                                                                              \
  }

  GEMM_STAGE(0, 0);
  __syncthreads();
  for (int t = 0; t < NT; t++) {
    const int bb = t & 1;
    if (t < NT - 1) GEMM_STAGE(bb ^ 1, (t + 1) * 64);
    const char* Ab = (const char*)&As[bb][0][0];
    const char* Bb = (const char*)&Bs[bb][0][0];
    f16x8 af[4][2], bf[2][2];
#pragma unroll
    for (int mi = 0; mi < 4; mi++) {
      const char* rb = Ab + (wr * 64 + mi * 16 + q) * 128;
      af[mi][0] = *(const f16x8*)(rb + ((g ^ swz) << 4));
      af[mi][1] = *(const f16x8*)(rb + (((4 + g) ^ swz) << 4));
    }
#pragma unroll
    for (int ni = 0; ni < 2; ni++) {
      const char* rb = Bb + (wc * 32 + ni * 16 + q) * 128;
      bf[ni][0] = *(const f16x8*)(rb + ((g ^ swz) << 4));
      bf[ni][1] = *(const f16x8*)(rb + (((4 + g) ^ swz) << 4));
    }
#pragma unroll
    for (int mi = 0; mi < 4; mi++)
#pragma unroll
      for (int ni = 0; ni < 2; ni++) {
        acc[mi][ni] = MFMA16(af[mi][0], bf[ni][0], acc[mi][ni]);
        acc[mi][ni] = MFMA16(af[mi][1], bf[ni][1], acc[mi][ni]);
      }
    __syncthreads();
  }
#pragma unroll
  for (int mi = 0; mi < 4; mi++)
#pragma unroll
    for (int ni = 0; ni < 2; ni++) {
      const int col = n0 + wc * 32 + ni * 16 + q;
      const float bv = bias[col];
#pragma unroll
      for (int r = 0; r < 4; r++) {
        const int row = m0 + wr * 64 + mi * 16 + g * 4 + r;
        const float val = acc[mi][ni][r] + bv;
        if (EPI == 0) {
          ((f16*)Cout)[(size_t)row * DMODEL + col] = (f16)val;
        } else if (EPI == 1) {
          const int bb2 = row >> 11, s = row & (SEQ - 1);
          const int hh = col >> 6, dh = col & 63;
          ((f16*)Cout)[((size_t)((bb2 * HEADS + hh) * DHEAD + dh) << 11) + s] = (f16)val;
        } else {
          ((float*)Cout)[(size_t)row * DMODEL + col] = val;
        }
      }
    }
}

// ---------------- flash-style attention, NO 1/sqrt(dk) scaling ----------------
// grid (S/64, B*H); 4 waves, each owns 16 q rows; KV tile = 64, double-buffered
// LDS shared by all waves. Swapped MFMAs: S^T = K·Q^T (softmax lane-local),
// O^T = V^T·P^T (rescale lane-local). Output stored in the reference's
// transpose-bug scramble: b'=h>>3, s'=((2h+b)&15)*128+s/16, d'=(s%16)*64+dh.
__global__ __launch_bounds__(256) void attn_kernel(
    const f16* __restrict__ Qp, const f16* __restrict__ Kp,
    const f16* __restrict__ Vt, f16* __restrict__ data_s) {
  __shared__ f16 Klds[2][64][64];
  __shared__ f16 Vlds[2][64][64];
  __shared__ f16 Plds[4][16][64];
  const int tid = threadIdx.x;
  const int w = tid >> 6, l = tid & 63, q = l & 15, g = l >> 4;
  const int bh = blockIdx.y, b = bh >> 4, h = bh & 15;
  const int q0 = blockIdx.x * 64 + w * 16;

  // Q fragment (B-layout): col = q, k(dh) = half*32 + 8g + i
  const f16* qrow = Qp + (size_t)(b * SEQ + q0 + q) * DMODEL + h * DHEAD;
  const f16x8 qf0 = *(const f16x8*)(qrow + g * 8);
  const f16x8 qf1 = *(const f16x8*)(qrow + 32 + g * 8);

  const int sr = l >> 3, sc8 = l & 7;
  const f16* kg = Kp + (size_t)b * SEQ * DMODEL + h * DHEAD;
  const f16* vg = Vt + (size_t)bh * DHEAD * SEQ;

  float m_st = -1.0e30f, l_st = 0.f;
  f32x4 o_acc[4] = {};

#define ATTN_STAGE(bb, kt)                                                         \
  {                                                                                \
    _Pragma("unroll")                                                              \
    for (int j = 0; j < 2; j++) {                                                  \
      const int rr_ = w * 16 + j * 8 + sr;                                         \
      const int cs_ = sc8 ^ (rr_ & 7);                                             \
      GLOBAL_LOAD_LDS16(kg + (size_t)((kt) + rr_) * DMODEL + cs_ * 8,              \
                        (char*)&Klds[bb][w * 16 + j * 8][0]);                      \
      GLOBAL_LOAD_LDS16(vg + (size_t)rr_ * SEQ + (kt) + cs_ * 8,                   \
                        (char*)&Vlds[bb][w * 16 + j * 8][0]);                      \
    }                                                                              \
  }

  ATTN_STAGE(0, 0);
  __syncthreads();

  const int swz = q & 7;
  for (int t = 0; t < SEQ / 64; t++) {
    const int bb = t & 1;
    if (t < SEQ / 64 - 1) ATTN_STAGE(bb ^ 1, (t + 1) * 64);

    // --- S^T tile: rows k (lane 4g+r per fn group), cols q (lane q) ---
    const char* Kb = (const char*)&Klds[bb][0][0];
    f32x4 sacc[4] = {};
#pragma unroll
    for (int fn = 0; fn < 4; fn++) {
      const char* rb = Kb + (fn * 16 + q) * 128;
      f16x8 a0 = *(const f16x8*)(rb + ((g ^ swz) << 4));
      f16x8 a1 = *(const f16x8*)(rb + (((4 + g) ^ swz) << 4));
      sacc[fn] = MFMA16(a0, qf0, sacc[fn]);
      sacc[fn] = MFMA16(a1, qf1, sacc[fn]);
    }
    // --- online softmax, lane-local row q; reduce over g via 2 shuffles ---
    float mx = fmaxf(fmaxf(fmaxf(sacc[0][0], sacc[0][1]), fmaxf(sacc[0][2], sacc[0][3])),
                     fmaxf(fmaxf(sacc[1][0], sacc[1][1]), fmaxf(sacc[1][2], sacc[1][3])));
    mx = fmaxf(mx, fmaxf(fmaxf(fmaxf(sacc[2][0], sacc[2][1]), fmaxf(sacc[2][2], sacc[2][3])),
                         fmaxf(fmaxf(sacc[3][0], sacc[3][1]), fmaxf(sacc[3][2], sacc[3][3]))));
    mx = fmaxf(mx, __shfl_xor(mx, 16, 64));
    mx = fmaxf(mx, __shfl_xor(mx, 32, 64));
    const float mnew = fmaxf(m_st, mx);
    const float sc = __expf(m_st - mnew);
    m_st = mnew;
    float ts = 0.f;
#pragma unroll
    for (int fn = 0; fn < 4; fn++)
#pragma unroll
      for (int r = 0; r < 4; r++) {
        const float pv = __expf(sacc[fn][r] - mnew);
        sacc[fn][r] = pv;
        ts += pv;
      }
    ts += __shfl_xor(ts, 16, 64);
    ts += __shfl_xor(ts, 32, 64);
    l_st = l_st * sc + ts;
#pragma unroll
    for (int fo = 0; fo < 4; fo++) {
      o_acc[fo][0] *= sc; o_acc[fo][1] *= sc;
      o_acc[fo][2] *= sc; o_acc[fo][3] *= sc;
    }
    // --- repack P through wave-private swizzled LDS (no barrier needed) ---
    char* Pb = (char*)&Plds[w][0][0] + q * 128;
#pragma unroll
    for (int fn = 0; fn < 4; fn++) {
      f16x4 pk;
      pk[0] = (f16)sacc[fn][0]; pk[1] = (f16)sacc[fn][1];
      pk[2] = (f16)sacc[fn][2]; pk[3] = (f16)sacc[fn][3];
      *(f16x4*)(Pb + ((((fn * 2 + (g >> 1)) ^ swz) << 4) + (g & 1) * 8)) = pk;
    }
    f16x8 p0 = *(const f16x8*)(Pb + ((g ^ swz) << 4));
    f16x8 p1 = *(const f16x8*)(Pb + (((4 + g) ^ swz) << 4));
    // --- O^T += V^T · P^T ---
    const char* Vb = (const char*)&Vlds[bb][0][0];
#pragma unroll
    for (int fo = 0; fo < 4; fo++) {
      const char* rb = Vb + (fo * 16 + q) * 128;
      f16x8 v0 = *(const f16x8*)(rb + ((g ^ swz) << 4));
      f16x8 v1 = *(const f16x8*)(rb + (((4 + g) ^ swz) << 4));
      o_acc[fo] = MFMA16(v0, p0, o_acc[fo]);
      o_acc[fo] = MFMA16(v1, p1, o_acc[fo]);
    }
    __syncthreads();
  }
  // --- finalize + scrambled store (lane holds O[q][dh=fo*16+4g+r]) ---
  const float inv = 1.f / l_st;
  const int s = q0 + q;
  const int m16 = (2 * h + b) & 15, bp = h >> 3;
  const int sp = m16 * 128 + (s >> 4);
  f16* outp = data_s + (size_t)(bp * SEQ + sp) * DMODEL + (s & 15) * 64 + g * 4;
#pragma unroll
  for (int fo = 0; fo < 4; fo++) {
    f16x4 ov;
    ov[0] = (f16)(o_acc[fo][0] * inv); ov[1] = (f16)(o_acc[fo][1] * inv);
    ov[2] = (f16)(o_acc[fo][2] * inv); ov[3] = (f16)(o_acc[fo][3] * inv);
    *(f16x4*)(outp + fo * 16) = ov;
  }
}

extern "C" void kernel_launch(void* const* d_in, const int* in_sizes, int n_in,
                              void* d_out, int out_size, void* d_ws, size_t ws_size,
                              hipStream_t stream) {
  const float* q  = (const float*)d_in[0];
  const float* k  = (const float*)d_in[1];
  const float* v  = (const float*)d_in[2];
  const float* wq = (const float*)d_in[3];
  const float* bq = (const float*)d_in[4];
  const float* wk = (const float*)d_in[5];
  const float* bk = (const float*)d_in[6];
  const float* wv = (const float*)d_in[7];
  const float* bv = (const float*)d_in[8];
  const float* wo = (const float*)d_in[9];
  const float* bo = (const float*)d_in[10];

  // workspace layout (40 MB total):
  // [0,8M)   xb   : f16 cast of q/k/v in turn, later the scrambled attn output
  // [8,16M)  Qp   [16,24M) Kp   [24,32M) Vt[b,h,dh,s]
  // [32,40M) wqt/wkt/wvt/wot (f16, transposed [N][K], 2MB each)
  uint8_t* ws = (uint8_t*)d_ws;
  f16* xb  = (f16*)(ws);
  f16* Qp  = (f16*)(ws + (8u << 20));
  f16* Kp  = (f16*)(ws + (16u << 20));
  f16* Vt  = (f16*)(ws + (24u << 20));
  f16* wqt = (f16*)(ws + (32u << 20));
  f16* wkt = (f16*)(ws + (34u << 20));
  f16* wvt = (f16*)(ws + (36u << 20));
  f16* wot = (f16*)(ws + (38u << 20));

  dim3 blk256(256);
  dim3 gT(16, 16, 4);
  dim3 gC(MTOK * DMODEL / 4 / 256);       // 4096 blocks
  dim3 gG(DMODEL / 64, MTOK / 128);       // (16, 32) = 512 blocks
  dim3 gA(SEQ / 64, BATCH * HEADS);       // (32, 32)

  transw_kernel<<<gT, blk256, 0, stream>>>(wq, wk, wv, wo, wqt, wkt, wvt, wot);

  cast_kernel<<<gC, blk256, 0, stream>>>(q, xb);
  gemm_kernel<0><<<gG, blk256, 0, stream>>>(xb, wqt, bq, Qp, DMODEL);

  cast_kernel<<<gC, blk256, 0, stream>>>(k, xb);
  gemm_kernel<0><<<gG, blk256, 0, stream>>>(xb, wkt, bk, Kp, DMODEL);

  cast_kernel<<<gC, blk256, 0, stream>>>(v, xb);
  gemm_kernel<1><<<gG, blk256, 0, stream>>>(xb, wvt, bv, Vt, DMODEL);

  attn_kernel<<<gA, blk256, 0, stream>>>(Qp, Kp, Vt, xb);
  gemm_kernel<2><<<gG, blk256, 0, stream>>>(xb, wot, bo, (float*)d_out, DMODEL);
}

// Round 3
// 247.216 us; speedup vs baseline: 1.8019x; 1.0820x over previous
//
#include <hip/hip_runtime.h>

typedef _Float16 f16;
typedef _Float16 f16x8 __attribute__((ext_vector_type(8)));
typedef _Float16 f16x4 __attribute__((ext_vector_type(4)));
typedef float    f32x4 __attribute__((ext_vector_type(4)));

static constexpr int BATCH = 2, SEQ = 2048, DMODEL = 1024, HEADS = 16, DHEAD = 64;
static constexpr int MTOK = BATCH * SEQ;  // 4096 tokens
static constexpr float LOG2E = 1.44269504088896f;

// async global->LDS, 16B per lane, LDS dest = wave-uniform base + lane*16
#define GLOBAL_LOAD_LDS16(gptr, lptr)                                              \
  __builtin_amdgcn_global_load_lds(                                                \
      (const __attribute__((address_space(1))) void*)(gptr),                       \
      (__attribute__((address_space(3))) void*)(lptr), 16, 0, 0)

#define MFMA16(a, b, c) __builtin_amdgcn_mfma_f32_16x16x32_f16((a), (b), (c), 0, 0, 0)

__device__ __forceinline__ float fexp2(float x) {
  float r;
  asm volatile("v_exp_f32 %0, %1" : "=v"(r) : "v"(x));
  return r;
}

// ---- 64x32 f16 image block (4KB = 2048 f16), paired-row XOR swizzle ----
// logical (mr in [0,64), kr in [0,32)) -> f16 offset within block.
// phys row pr = mr>>1 (128B rows of 8 chunks); chunk jj = (mr&1)*4 + kr/8,
// stored at j = jj ^ (pr&7). Conflict-free for 16-row x 8-f16 fragment reads.
__device__ __forceinline__ int imgAB(int mr, int kr) {
  int pr = mr >> 1;
  int jj = ((mr & 1) << 2) | (kr >> 3);
  int j = jj ^ (pr & 7);
  return pr * 64 + j * 8 + (kr & 7);
}
// K image: 32 s-rows x 64 dh, full-row swizzle
__device__ __forceinline__ int imgK(int sr, int dh) {
  return sr * 64 + (((dh >> 3) ^ (sr & 7)) << 3) + (dh & 7);
}

// ---------------- cast fp32 -> f16 image layout ----------------
// one 16B chunk per thread; dest linear (coalesced), source 32B runs.
__global__ __launch_bounds__(256) void cast_kernel(const float* __restrict__ src,
                                                   f16* __restrict__ dst) {
  int c = blockIdx.x * 256 + threadIdx.x;  // chunk id, 524288 total
  int blk = c >> 8, cb = c & 255;
  int pr = cb >> 3, j = cb & 7;
  int jj = j ^ (pr & 7);
  int mr = (pr << 1) | (jj >> 2);
  int kr = (jj & 3) << 3;
  int m = (blk >> 5) * 64 + mr;
  int k = (blk & 31) * 32 + kr;
  const float* s = src + (size_t)m * DMODEL + k;
  f32x4 a = *(const f32x4*)s, b = *(const f32x4*)(s + 4);
  f16x8 o;
  o[0] = (f16)a[0]; o[1] = (f16)a[1]; o[2] = (f16)a[2]; o[3] = (f16)a[3];
  o[4] = (f16)b[0]; o[5] = (f16)b[1]; o[6] = (f16)b[2]; o[7] = (f16)b[3];
  *(f16x8*)(dst + (size_t)c * 8) = o;
}

// ------------- weight transpose+cast to image: B[n][k] = w[k][n] -------------
__global__ __launch_bounds__(256) void transw_kernel(
    const float* __restrict__ w0, const float* __restrict__ w1,
    const float* __restrict__ w2, const float* __restrict__ w3,
    f16* __restrict__ Wimg) {
  const int z = blockIdx.z;
  const float* w = z == 0 ? w0 : z == 1 ? w1 : z == 2 ? w2 : w3;
  f16* t = Wimg + (size_t)z * DMODEL * DMODEL;
  __shared__ f16 lt[64][72];
  const int k0 = blockIdx.x * 64, n0 = blockIdx.y * 64;
  const int r = threadIdx.x >> 2, c0 = (threadIdx.x & 3) * 16;
  const float* src = w + (size_t)(k0 + r) * DMODEL + n0 + c0;
#pragma unroll
  for (int jx = 0; jx < 16; jx += 4) {
    f32x4 x = *(const f32x4*)(src + jx);
    lt[c0 + jx + 0][r] = (f16)x[0];
    lt[c0 + jx + 1][r] = (f16)x[1];
    lt[c0 + jx + 2][r] = (f16)x[2];
    lt[c0 + jx + 3][r] = (f16)x[3];
  }
  __syncthreads();
  const int n = n0 + r;
#pragma unroll
  for (int cw = 0; cw < 2; cw++) {
    int k = k0 + c0 + cw * 8;
    int blk = ((n >> 6) << 5) | (k >> 5);
    int off = blk * 2048 + imgAB(n & 63, k & 31);
    f16x8 v;
#pragma unroll
    for (int e = 0; e < 8; e++) v[e] = lt[r][c0 + cw * 8 + e];
    *(f16x8*)(t + off) = v;
  }
}

// ------- fused QKV projection GEMM: 128x128 tile, BK=32, 4 waves, z-fused ------
// z=0: Qp linear f16, scaled by log2(e).  z=1: Kp in K-image tiles per (b,h).
// z=2: Vt in V-image tiles (dh-major).  A/B staged linearly from image layouts.
__global__ __launch_bounds__(256) void proj_kernel(
    const f16* __restrict__ Ximg, const f16* __restrict__ Wimg,
    const float* __restrict__ bq, const float* __restrict__ bk,
    const float* __restrict__ bv, f16* __restrict__ Qp, f16* __restrict__ Kp,
    f16* __restrict__ Vt, int zbase, size_t aStride) {
  __shared__ f16 As[4096];  // 2 image blocks (128 m-rows x 32 k)
  __shared__ f16 Bs[4096];
  const int z = zbase + blockIdx.z;
  const f16* A = Ximg + (size_t)blockIdx.z * aStride;
  const f16* Bw = Wimg + (size_t)z * DMODEL * DMODEL;
  // XCD-aware bijective swizzle (nwg=256 per z)
  int lin = blockIdx.x + (blockIdx.y << 3);
  int swz = ((lin & 7) << 5) + (lin >> 3);
  const int n0 = (swz & 7) * 128, m0 = (swz >> 3) * 128;
  const int tid = threadIdx.x, w = tid >> 6, l = tid & 63, q = l & 15, g = l >> 4;
  const int wr = w >> 1, wc = w & 1;
  const int KT = DMODEL >> 5;  // 32 k-tiles
  int aoff[4], boff[4];
#pragma unroll
  for (int mi = 0; mi < 4; mi++) {
    int mr = wr * 64 + mi * 16 + q;
    aoff[mi] = ((mr >> 6) << 11) + imgAB(mr & 63, g * 8);
  }
#pragma unroll
  for (int ni = 0; ni < 4; ni++) {
    int nr = wc * 64 + ni * 16 + q;
    boff[ni] = ((nr >> 6) << 11) + imgAB(nr & 63, g * 8);
  }
  f32x4 acc[4][4] = {};
  for (int t = 0; t < KT; t++) {
#pragma unroll
    for (int i = 0; i < 2; i++) {
      int c = w * 2 + i;
      GLOBAL_LOAD_LDS16(A + (size_t)(((m0 >> 6) + (c >> 2)) * KT + t) * 2048 + (c & 3) * 512 + l * 8,
                        (char*)&As[c * 512]);
      GLOBAL_LOAD_LDS16(Bw + (size_t)(((n0 >> 6) + (c >> 2)) * KT + t) * 2048 + (c & 3) * 512 + l * 8,
                        (char*)&Bs[c * 512]);
    }
    __syncthreads();
    f16x8 af[4], bf[4];
#pragma unroll
    for (int mi = 0; mi < 4; mi++) af[mi] = *(const f16x8*)&As[aoff[mi]];
#pragma unroll
    for (int ni = 0; ni < 4; ni++) bf[ni] = *(const f16x8*)&Bs[boff[ni]];
#pragma unroll
    for (int mi = 0; mi < 4; mi++)
#pragma unroll
      for (int ni = 0; ni < 4; ni++)
        acc[mi][ni] = MFMA16(af[mi], bf[ni], acc[mi][ni]);
    __syncthreads();
  }
  const float* bias = z == 0 ? bq : (z == 1 ? bk : bv);
#pragma unroll
  for (int mi = 0; mi < 4; mi++)
#pragma unroll
    for (int ni = 0; ni < 4; ni++) {
      const int col = n0 + wc * 64 + ni * 16 + q;
      const float bvl = bias[col];
      const int row0 = m0 + wr * 64 + mi * 16 + g * 4;
      if (z == 0) {
#pragma unroll
        for (int r = 0; r < 4; r++)
          Qp[(size_t)(row0 + r) * DMODEL + col] = (f16)((acc[mi][ni][r] + bvl) * LOG2E);
      } else if (z == 1) {
        const int h = col >> 6, dh = col & 63;
#pragma unroll
        for (int r = 0; r < 4; r++) {
          const int row = row0 + r, s = row & (SEQ - 1);
          Kp[(size_t)(((row >> 11) * HEADS + h) * 64 + (s >> 5)) * 2048 + imgK(s & 31, dh)] =
              (f16)(acc[mi][ni][r] + bvl);
        }
      } else {
        const int h = col >> 6, dh = col & 63;
        const int s0 = row0 & (SEQ - 1);
        f16* dst = Vt + (size_t)(((row0 >> 11) * HEADS + h) * 64 + (s0 >> 5)) * 2048 +
                   imgAB(dh, s0 & 31);
        f16x4 ov;
        ov[0] = (f16)(acc[mi][ni][0] + bvl); ov[1] = (f16)(acc[mi][ni][1] + bvl);
        ov[2] = (f16)(acc[mi][ni][2] + bvl); ov[3] = (f16)(acc[mi][ni][3] + bvl);
        *(f16x4*)dst = ov;
      }
    }
}

// ---------------- flash attention (scores pre-scaled by log2e) ----------------
// grid 1024 blocks, 4 waves x 16 q-rows, KVBLK=32, LDS=20KB (4 blocks/CU).
// Swapped MFMAs keep softmax lane-local; defer-max skips rescale on most tiles.
// Output written directly in out-GEMM A-image layout with the reference's
// transpose-bug scramble: b'=h>>3, s'=((2h+b)&15)*128+s/16, d'=(s%16)*64+dh.
__global__ __launch_bounds__(256) void attn_kernel(
    const f16* __restrict__ Qp, const f16* __restrict__ Kimg,
    const f16* __restrict__ Vimg, f16* __restrict__ Simg) {
  __shared__ f16 Klds[2][2048];
  __shared__ f16 Vlds[2][2048];
  __shared__ f16 Plds[4][512];
  const int tid = threadIdx.x, w = tid >> 6, l = tid & 63, q = l & 15, g = l >> 4;
  int lin = blockIdx.x + (blockIdx.y << 5);
  int swz = ((lin & 7) << 7) + (lin >> 3);
  const int qb = swz & 31, bh = swz >> 5;
  const int b = bh >> 4, h = bh & 15;
  const int q0 = qb * 64 + w * 16;
  const f16* qrow = Qp + (size_t)(b * SEQ + q0 + q) * DMODEL + h * 64;
  const f16x8 qf0 = *(const f16x8*)(qrow + g * 8);
  const f16x8 qf1 = *(const f16x8*)(qrow + 32 + g * 8);
  const f16* kt_base = Kimg + (size_t)(bh * 64) * 2048;
  const f16* vt_base = Vimg + (size_t)(bh * 64) * 2048;
  int koff[2][2];
#pragma unroll
  for (int fn = 0; fn < 2; fn++)
#pragma unroll
    for (int hf = 0; hf < 2; hf++) koff[fn][hf] = imgK(fn * 16 + q, hf * 32 + g * 8);
  int voff[4];
#pragma unroll
  for (int fo = 0; fo < 4; fo++) voff[fo] = imgAB(fo * 16 + q, g * 8);
  const int poff = imgAB(q, g * 8);
  int pwoff[2];
  {
    const int pr = q >> 1;
#pragma unroll
    for (int fn = 0; fn < 2; fn++) {
      int jj = ((q & 1) << 2) | (fn * 2 + (g >> 1));
      pwoff[fn] = pr * 64 + ((jj ^ (pr & 7)) << 3) + (g & 1) * 4;
    }
  }
  f16* Pw = &Plds[w][0];
  float m_st = -1.0e30f, l_pt = 0.f;
  f32x4 o_acc[4] = {};

  GLOBAL_LOAD_LDS16(kt_base + w * 512 + l * 8, (char*)&Klds[0][w * 512]);
  GLOBAL_LOAD_LDS16(vt_base + w * 512 + l * 8, (char*)&Vlds[0][w * 512]);
  __syncthreads();

  for (int t = 0; t < 64; t++) {
    const int bb = t & 1;
    if (t < 63) {
      GLOBAL_LOAD_LDS16(kt_base + (size_t)(t + 1) * 2048 + w * 512 + l * 8,
                        (char*)&Klds[bb ^ 1][w * 512]);
      GLOBAL_LOAD_LDS16(vt_base + (size_t)(t + 1) * 2048 + w * 512 + l * 8,
                        (char*)&Vlds[bb ^ 1][w * 512]);
    }
    const f16* Kb = &Klds[bb][0];
    const f16* Vb = &Vlds[bb][0];
    f32x4 s0 = {}, s1 = {};
    s0 = MFMA16(*(const f16x8*)(Kb + koff[0][0]), qf0, s0);
    s0 = MFMA16(*(const f16x8*)(Kb + koff[0][1]), qf1, s0);
    s1 = MFMA16(*(const f16x8*)(Kb + koff[1][0]), qf0, s1);
    s1 = MFMA16(*(const f16x8*)(Kb + koff[1][1]), qf1, s1);
    float lm = fmaxf(fmaxf(fmaxf(s0[0], s0[1]), fmaxf(s0[2], s0[3])),
                     fmaxf(fmaxf(s1[0], s1[1]), fmaxf(s1[2], s1[3])));
    if (!__all(lm <= m_st + 8.f)) {
      float mx = lm;
      mx = fmaxf(mx, __shfl_xor(mx, 16, 64));
      mx = fmaxf(mx, __shfl_xor(mx, 32, 64));
      const float mnew = fmaxf(m_st, mx);
      const float sc = fexp2(m_st - mnew);
      m_st = mnew;
      l_pt *= sc;
#pragma unroll
      for (int fo = 0; fo < 4; fo++) {
        o_acc[fo][0] *= sc; o_acc[fo][1] *= sc;
        o_acc[fo][2] *= sc; o_acc[fo][3] *= sc;
      }
    }
    f16x4 pa, pb;
    float ts = 0.f;
#pragma unroll
    for (int r = 0; r < 4; r++) {
      float e0 = fexp2(s0[r] - m_st);
      float e1 = fexp2(s1[r] - m_st);
      ts += e0 + e1;
      pa[r] = (f16)e0;
      pb[r] = (f16)e1;
    }
    l_pt += ts;
    *(f16x4*)(Pw + pwoff[0]) = pa;
    *(f16x4*)(Pw + pwoff[1]) = pb;
    const f16x8 pf = *(const f16x8*)(Pw + poff);
#pragma unroll
    for (int fo = 0; fo < 4; fo++)
      o_acc[fo] = MFMA16(*(const f16x8*)(Vb + voff[fo]), pf, o_acc[fo]);
    __syncthreads();
  }
  float lsum = l_pt + __shfl_xor(l_pt, 16, 64);
  lsum += __shfl_xor(lsum, 32, 64);
  const float inv = 1.f / lsum;
  const int s = q0 + q;
  const int m16 = (2 * h + b) & 15, bp = h >> 3;
  const int tp = bp * SEQ + m16 * 128 + (s >> 4);  // scrambled token index
#pragma unroll
  for (int fo = 0; fo < 4; fo++) {
    const int d0 = (s & 15) * 64 + fo * 16 + g * 4;
    f16* dst = Simg + (size_t)(((tp >> 6) << 5) | (d0 >> 5)) * 2048 + imgAB(tp & 63, d0 & 31);
    f16x4 ov;
    ov[0] = (f16)(o_acc[fo][0] * inv); ov[1] = (f16)(o_acc[fo][1] * inv);
    ov[2] = (f16)(o_acc[fo][2] * inv); ov[3] = (f16)(o_acc[fo][3] * inv);
    *(f16x4*)dst = ov;
  }
}

// ------------- output GEMM: 128x64 tile, BK=32, f32 out + bias -------------
__global__ __launch_bounds__(256) void ogemm_kernel(
    const f16* __restrict__ Aimg, const f16* __restrict__ Bimg,
    const float* __restrict__ bias, float* __restrict__ out) {
  __shared__ f16 As[4096];
  __shared__ f16 Bs[2048];
  int lin = blockIdx.x + (blockIdx.y << 4);
  int swz = ((lin & 7) << 6) + (lin >> 3);
  const int n0 = (swz & 15) * 64, m0 = (swz >> 4) * 128;
  const int tid = threadIdx.x, w = tid >> 6, l = tid & 63, q = l & 15, g = l >> 4;
  const int wr = w >> 1, wc = w & 1;
  int aoff[4], boff[2];
#pragma unroll
  for (int mi = 0; mi < 4; mi++) {
    int mr = wr * 64 + mi * 16 + q;
    aoff[mi] = ((mr >> 6) << 11) + imgAB(mr & 63, g * 8);
  }
#pragma unroll
  for (int ni = 0; ni < 2; ni++) boff[ni] = imgAB(wc * 32 + ni * 16 + q, g * 8);
  f32x4 acc[4][2] = {};
  for (int t = 0; t < 32; t++) {
#pragma unroll
    for (int i = 0; i < 2; i++) {
      int c = w * 2 + i;
      GLOBAL_LOAD_LDS16(Aimg + (size_t)(((m0 >> 6) + (c >> 2)) * 32 + t) * 2048 + (c & 3) * 512 + l * 8,
                        (char*)&As[c * 512]);
    }
    GLOBAL_LOAD_LDS16(Bimg + ((size_t)(n0 >> 6) * 32 + t) * 2048 + w * 512 + l * 8,
                      (char*)&Bs[w * 512]);
    __syncthreads();
    f16x8 af[4], bf[2];
#pragma unroll
    for (int mi = 0; mi < 4; mi++) af[mi] = *(const f16x8*)&As[aoff[mi]];
#pragma unroll
    for (int ni = 0; ni < 2; ni++) bf[ni] = *(const f16x8*)&Bs[boff[ni]];
#pragma unroll
    for (int mi = 0; mi < 4; mi++)
#pragma unroll
      for (int ni = 0; ni < 2; ni++)
        acc[mi][ni] = MFMA16(af[mi], bf[ni], acc[mi][ni]);
    __syncthreads();
  }
#pragma unroll
  for (int mi = 0; mi < 4; mi++)
#pragma unroll
    for (int ni = 0; ni < 2; ni++) {
      const int col = n0 + wc * 32 + ni * 16 + q;
      const float bvl = bias[col];
      const int row0 = m0 + wr * 64 + mi * 16 + g * 4;
#pragma unroll
      for (int r = 0; r < 4; r++)
        out[(size_t)(row0 + r) * DMODEL + col] = acc[mi][ni][r] + bvl;
    }
}

extern "C" void kernel_launch(void* const* d_in, const int* in_sizes, int n_in,
                              void* d_out, int out_size, void* d_ws, size_t ws_size,
                              hipStream_t stream) {
  const float* q  = (const float*)d_in[0];
  const float* k  = (const float*)d_in[1];
  const float* v  = (const float*)d_in[2];
  const float* wq = (const float*)d_in[3];
  const float* bq = (const float*)d_in[4];
  const float* wk = (const float*)d_in[5];
  const float* bk = (const float*)d_in[6];
  const float* wv = (const float*)d_in[7];
  const float* bv = (const float*)d_in[8];
  const float* wo = (const float*)d_in[9];
  const float* bo = (const float*)d_in[10];

  const size_t XSZ = (size_t)MTOK * DMODEL;  // 4M f16 = 8MB
  f16* ws = (f16*)d_ws;
  const bool fused = ws_size >= (56ull << 20);

  f16 *X0, *X1, *X2, *Qp, *Kp, *Vt, *Wimg, *scr;
  if (fused) {
    X0 = ws; X1 = ws + XSZ; X2 = ws + 2 * XSZ;
    Qp = ws + 3 * XSZ; Kp = ws + 4 * XSZ; Vt = ws + 5 * XSZ;
    Wimg = ws + 6 * XSZ;
    scr = X0;
  } else {
    X0 = X1 = X2 = ws;
    Qp = ws + XSZ; Kp = ws + 2 * XSZ; Vt = ws + 3 * XSZ;
    Wimg = ws + 4 * XSZ;
    scr = X0;
  }

  dim3 blk(256);
  dim3 gT(16, 16, 4);
  dim3 gC(2048);
  dim3 gA(32, 32);
  dim3 gO(16, 32);

  transw_kernel<<<gT, blk, 0, stream>>>(wq, wk, wv, wo, Wimg);

  if (fused) {
    cast_kernel<<<gC, blk, 0, stream>>>(q, X0);
    cast_kernel<<<gC, blk, 0, stream>>>(k, X1);
    cast_kernel<<<gC, blk, 0, stream>>>(v, X2);
    proj_kernel<<<dim3(8, 32, 3), blk, 0, stream>>>(X0, Wimg, bq, bk, bv, Qp, Kp, Vt, 0, XSZ);
  } else {
    cast_kernel<<<gC, blk, 0, stream>>>(q, X0);
    proj_kernel<<<dim3(8, 32, 1), blk, 0, stream>>>(X0, Wimg, bq, bk, bv, Qp, Kp, Vt, 0, 0);
    cast_kernel<<<gC, blk, 0, stream>>>(k, X0);
    proj_kernel<<<dim3(8, 32, 1), blk, 0, stream>>>(X0, Wimg, bq, bk, bv, Qp, Kp, Vt, 1, 0);
    cast_kernel<<<gC, blk, 0, stream>>>(v, X0);
    proj_kernel<<<dim3(8, 32, 1), blk, 0, stream>>>(X0, Wimg, bq, bk, bv, Qp, Kp, Vt, 2, 0);
  }

  attn_kernel<<<gA, blk, 0, stream>>>(Qp, Kp, Vt, scr);
  ogemm_kernel<<<gO, blk, 0, stream>>>(scr, Wimg + (size_t)3 * DMODEL * DMODEL, bo, (float*)d_out);
}